// Round 13
// baseline (349.240 us; speedup 1.0000x reference)
//
#include <hip/hip_runtime.h>
#include <hip/hip_bf16.h>

// Problem constants (fixed by setup_inputs)
#define NB 16     // batch
#define CC 64     // channels
#define TT 64
#define VV 25
#define LL 1600   // T*V
#define HH 4
#define DD 64
#define NH 64     // N*H

// Dtype contract (established rounds 0-3): d_in fp32, d_out fp32,
// tolerance bf16-grade (2% * max|ref|) -> internal bf16 pipeline OK.

typedef __hip_bfloat16 bf16;
typedef __attribute__((ext_vector_type(8))) short short8;
typedef __attribute__((ext_vector_type(4))) short s16x4;  // 'short4' is HIP's struct
typedef __attribute__((ext_vector_type(4))) float f32x4;
typedef __attribute__((ext_vector_type(4))) unsigned short us4;

// 16x16x16 bf16 MFMA (A/B: 4 bf16 = 2 VGPRs; C/D: 4 f32). The _1k builtin is
// device-only: HIP's HOST pass doesn't declare it (round-12 failure), so give
// the host a type-correct stub that is never executed.
#if defined(__HIP_DEVICE_COMPILE__)
#define MFMA16(A, B, C) __builtin_amdgcn_mfma_f32_16x16x16bf16_1k((A), (B), (C), 0, 0, 0)
#else
#define MFMA16(A, B, C) (C)
#endif

__device__ __forceinline__ float b2f(bf16 v) { return __bfloat162float(v); }
__device__ __forceinline__ unsigned short f2bf_bits(float f) {
  bf16 h = __float2bfloat16(f);
  return *(unsigned short*)&h;
}
// pack two f32 -> bf16x2 by truncation: one v_perm_b32 (bytes [hi.3 hi.2 lo.3 lo.2])
__device__ __forceinline__ unsigned pkbf_trunc(float lo, float hi) {
  return __builtin_amdgcn_perm(__float_as_uint(hi), __float_as_uint(lo), 0x07060302u);
}
// xor-1 lane exchange via DPP quad_perm [1,0,3,2] (0xB1): VALU, not LDS.
__device__ __forceinline__ int dppx1i(int x) {
  return __builtin_amdgcn_mov_dpp(x, 0xB1, 0xF, 0xF, true);
}

// ---------------------------------------------------------------------------
// K0: weight prep (unchanged from round 10).
// ---------------------------------------------------------------------------
__global__ void k_prep(const float* __restrict__ Wo, const float* __restrict__ Wf,
                       const float* __restrict__ Wq,
                       bf16* __restrict__ Wt, bf16* __restrict__ WfT,
                       bf16* __restrict__ WqT) {
  int i = blockIdx.x * 256 + threadIdx.x;
  if (i < 147456) {
    int j = i & 7, lane = (i >> 3) & 63, cot = (i >> 9) & 3;
    int kc = (i >> 11) & 7, r = i >> 14;
    int co = cot * 16 + (lane & 15);
    int ci = kc * 32 + (lane >> 4) * 8 + j;
    Wt[i] = __float2bfloat16(Wo[(co * 256 + ci) * 9 + r]);
  }
  if (i < 4096) {
    int j = i & 7, lane = (i >> 3) & 63, cot = (i >> 9) & 3, kc = (i >> 11) & 1;
    int co = cot * 16 + (lane & 15);
    int ci = kc * 32 + (lane >> 4) * 8 + j;
    WfT[i] = __float2bfloat16(Wf[co * 64 + ci]);
  }
  if (i < 49152) {
    int jj = i & 7, lane = (i >> 3) & 63, g = i >> 9;  // g 0..95
    int nt = g % 48, half = g / 48;
    int ch = half * 32 + (lane >> 4) * 8 + jj;
    int j = nt * 16 + (lane & 15);
    WqT[i] = __float2bfloat16(Wq[ch * 768 + j]);
  }
}

// ---------------------------------------------------------------------------
// K1: qkv projection as MFMA GEMM (unchanged from round 10).
// ---------------------------------------------------------------------------
__global__ __launch_bounds__(64)
void k_qkv(const float* __restrict__ x, const bf16* __restrict__ WqT,
           const float* __restrict__ bq,
           bf16* __restrict__ q, bf16* __restrict__ k, bf16* __restrict__ vt) {
  __shared__ short xa[16 * 72];  // A-tile [16 l][64 c] (+pad)
  __shared__ short tr[16 * 66];  // transpose buffer for q/k epilogue
  int lane = threadIdx.x;
  int quad = lane >> 4, c = lane & 15;
  int n = blockIdx.x / 100;
  int l0 = (blockIdx.x % 100) * 16;
  bool ev = (c & 1) == 0;

  {
    int l = c;
    const float* xb = x + (size_t)n * 102400 + (size_t)(quad * 16) * 1600 + l0 + l;
    unsigned short vb[16];
#pragma unroll
    for (int i = 0; i < 16; i++) vb[i] = f2bf_bits(xb[(size_t)i * 1600]);
    unsigned wrds[8];
#pragma unroll
    for (int i = 0; i < 8; i++)
      wrds[i] = ((unsigned)vb[2 * i + 1] << 16) | vb[2 * i];
    *(short8*)(xa + l * 72 + quad * 16) = *(short8*)&wrds[0];
    *(short8*)(xa + l * 72 + quad * 16 + 8) = *(short8*)&wrds[4];
  }
  asm volatile("" ::: "memory");
  short8 af0 = *(const short8*)(xa + c * 72 + quad * 8);
  short8 af1 = *(const short8*)(xa + c * 72 + 32 + quad * 8);

  const short* wq0 = (const short*)WqT;
  const float QSCALE = 0.125f * 1.44269504f;

#pragma unroll
  for (int s = 0; s < 2; s++) {
#pragma unroll
    for (int h = 0; h < 4; h++) {
      asm volatile("" ::: "memory");
#pragma unroll
      for (int t = 0; t < 4; t++) {
        int nt = s * 16 + h * 4 + t;
        float bv = bq[nt * 16 + c];
        f32x4 z = {bv, bv, bv, bv};
        short8 b0 = *(const short8*)(wq0 + ((size_t)nt * 64 + lane) * 8);
        short8 b1 = *(const short8*)(wq0 + ((size_t)(48 + nt) * 64 + lane) * 8);
        z = __builtin_amdgcn_mfma_f32_16x16x32_bf16(af0, b0, z, 0, 0, 0);
        z = __builtin_amdgcn_mfma_f32_16x16x32_bf16(af1, b1, z, 0, 0, 0);
        if (s == 0) {
#pragma unroll
          for (int r = 0; r < 4; r++) z[r] *= QSCALE;
        }
        int us_[4];
#pragma unroll
        for (int r = 0; r < 4; r++) us_[r] = f2bf_bits(z[r]);
        int xv0 = dppx1i(us_[0]);
        int xv1 = dppx1i(us_[1]);
        int xv2 = dppx1i(us_[2]);
        int xv3 = dppx1i(us_[3]);
        if (ev) {
          *(int*)(tr + (quad * 4 + 0) * 66 + t * 16 + c) = (xv0 << 16) | us_[0];
          *(int*)(tr + (quad * 4 + 1) * 66 + t * 16 + c) = (xv1 << 16) | us_[1];
        } else {
          *(int*)(tr + (quad * 4 + 2) * 66 + t * 16 + (c - 1)) = (us_[2] << 16) | xv2;
          *(int*)(tr + (quad * 4 + 3) * 66 + t * 16 + (c - 1)) = (us_[3] << 16) | xv3;
        }
      }
      asm volatile("" ::: "memory");
      int row = lane >> 2, seg = lane & 3;
      short8 o0 = *(const short8*)(tr + row * 66 + seg * 16);
      short8 o1 = *(const short8*)(tr + row * 66 + seg * 16 + 8);
      short* dstp = (short*)(s == 0 ? q : k);
      short* dst = dstp + ((size_t)(n * 4 + h) * 1600 + l0 + row) * 64 + seg * 16;
      *(short8*)(dst) = o0;
      *(short8*)(dst + 8) = o1;
    }
  }
#pragma unroll
  for (int h = 0; h < 4; h++) {
#pragma unroll
    for (int t = 0; t < 4; t++) {
      int nt = 32 + h * 4 + t;
      float bv = bq[nt * 16 + c];
      f32x4 z = {bv, bv, bv, bv};
      short8 b0 = *(const short8*)(wq0 + ((size_t)nt * 64 + lane) * 8);
      short8 b1 = *(const short8*)(wq0 + ((size_t)(48 + nt) * 64 + lane) * 8);
      z = __builtin_amdgcn_mfma_f32_16x16x32_bf16(af0, b0, z, 0, 0, 0);
      z = __builtin_amdgcn_mfma_f32_16x16x32_bf16(af1, b1, z, 0, 0, 0);
      us4 pk;
#pragma unroll
      for (int r = 0; r < 4; r++) pk[r] = f2bf_bits(z[r]);
      *(us4*)((short*)vt + ((size_t)((n * 4 + h) * 64 + t * 16 + c)) * 1600 +
              l0 + quad * 4) = pk;
    }
  }
}

// ---------------------------------------------------------------------------
// K2: MFMA flash attention, round-13 (= round-11 logic; host-pass fix only).
// TRANSPOSED orientation kills the P LDS round-trip: QK computed as
// S'[kv][qrow] (A=K, B=Q). The 16x16x16 bf16 B-fragment layout
// [n=lane&15][k=quad*4+j] EQUALS the C/D layout [col=lane&15][row=quad*4+reg],
// so exp2'd scores become the PV B-operand with one v_perm pack per pair
// (truncation; tolerance margin 3.4x). PV: O'[d][qrow] = V'.P' via 16x16x16
// MFMAs (A=V' straight from vt[d][l]). l-tile: A=all-ones -> every lane holds
// its own column's sum (no shfl). Epilogue: O' rows = output channels ->
// direct 8B stores, no LDS. K tile LDS-staged with 1-iter prefetch; XCD
// swizzle kept (FETCH at compulsory since round 10). grid 1600, block 128.
// ---------------------------------------------------------------------------
__global__ __launch_bounds__(128, 2)
void k_attn(const bf16* __restrict__ q, const bf16* __restrict__ k,
            const bf16* __restrict__ vt, bf16* __restrict__ ot) {
  __shared__ short kbuf[64 * 72];  // K tile, padded rows
  int tid = threadIdx.x;
  int wv = tid >> 6, lane = tid & 63;
  int quad = lane >> 4, c = lane & 15;
  int bid = blockIdx.x;            // 0..1599
  int xcd = bid & 7;
  int slot = bid >> 3;             // 0..199
  int qt = slot % 25;
  int nh = (slot / 25) * 8 + xcd;  // nh%8 == bid%8 -> per-XCD K/V stream
  int l0 = qt * 64 + wv * 32;      // wave's rows: tiles at l0, l0+16

  // Q fragments (B-operand of QK'): B[n=qrow][k=d]
  const short* qbase = (const short*)q + ((size_t)nh * 1600 + l0 + c) * 64 + quad * 8;
  short8 qf[2][2];
  qf[0][0] = *(const short8*)(qbase);
  qf[0][1] = *(const short8*)(qbase + 32);
  qf[1][0] = *(const short8*)(qbase + 16 * 64);
  qf[1][1] = *(const short8*)(qbase + 16 * 64 + 32);

  const short one2 = (short)0x3F80;
  s16x4 ones4 = {one2, one2, one2, one2};  // all-ones A for l row-sums

  f32x4 acc[2][4] = {};   // O'[tt][dt]: col=qrow, row=d_local
  f32x4 accl[2] = {};     // l[tt]: col=qrow (all regs identical)

  const short* kg = (const short*)k + (size_t)nh * 102400;
  const short* vg = (const short*)vt + (size_t)nh * 102400;

  // prologue: staging loads for kt=0
  short8 sk[4];
  {
    const short8* gk = (const short8*)kg;
#pragma unroll
    for (int i = 0; i < 4; i++) sk[i] = gk[tid + i * 128];
  }

  for (int kt = 0; kt < 25; kt++) {
    __syncthreads();  // kbuf reads of iter kt-1 done
#pragma unroll
    for (int i = 0; i < 4; i++) {
      int ch = tid + i * 128;
      *(short8*)(kbuf + (ch >> 3) * 72 + (ch & 7) * 8) = sk[i];
    }
    __syncthreads();  // kbuf(kt) visible
    // --- V A-frags: A[m=d][k=kv]; 8B loads, issued first to drain early ---
    s16x4 vf[4][4];  // [dt][kvt]
#pragma unroll
    for (int dt = 0; dt < 4; dt++) {
      const short* vrow = vg + (size_t)(dt * 16 + c) * 1600 + kt * 64 + quad * 4;
#pragma unroll
      for (int kvt = 0; kvt < 4; kvt++)
        vf[dt][kvt] = *(const s16x4*)(vrow + kvt * 16);
    }
    if (kt < 24) {  // K staging loads for kt+1
      const short8* gk = (const short8*)(kg + (kt + 1) * 4096);
#pragma unroll
      for (int i = 0; i < 4; i++) sk[i] = gk[tid + i * 128];
    }
    // --- S' = K.Q^T (A=K-frag from LDS, B=Q-frag), C init -8 (bias) ---
    f32x4 s[2][4];
#pragma unroll
    for (int ct = 0; ct < 4; ct++) {
      short8 kf0 = *(const short8*)(kbuf + (ct * 16 + c) * 72 + quad * 8);
      short8 kf1 = *(const short8*)(kbuf + (ct * 16 + c) * 72 + 32 + quad * 8);
      f32x4 z0 = {-8.f, -8.f, -8.f, -8.f}, z1 = {-8.f, -8.f, -8.f, -8.f};
      z0 = __builtin_amdgcn_mfma_f32_16x16x32_bf16(kf0, qf[0][0], z0, 0, 0, 0);
      z0 = __builtin_amdgcn_mfma_f32_16x16x32_bf16(kf1, qf[0][1], z0, 0, 0, 0);
      z1 = __builtin_amdgcn_mfma_f32_16x16x32_bf16(kf0, qf[1][0], z1, 0, 0, 0);
      z1 = __builtin_amdgcn_mfma_f32_16x16x32_bf16(kf1, qf[1][1], z1, 0, 0, 0);
      s[0][ct] = z0;
      s[1][ct] = z1;
    }
    // --- p = exp2(s'); pack in-register into PV B-frags (1 v_perm/pair) ---
#pragma unroll
    for (int tt = 0; tt < 2; tt++) {
#pragma unroll
      for (int ct = 0; ct < 4; ct++) {
        float p0 = exp2f(s[tt][ct][0]);
        float p1 = exp2f(s[tt][ct][1]);
        float p2 = exp2f(s[tt][ct][2]);
        float p3 = exp2f(s[tt][ct][3]);
        unsigned u2[2];
        u2[0] = pkbf_trunc(p0, p1);
        u2[1] = pkbf_trunc(p2, p3);
        s16x4 pfr = *(s16x4*)u2;  // B[n=qrow][k=kv(ct tile)]
        // PV: O'[dt] += V'[dt][ct-kv] . P'
#pragma unroll
        for (int dt = 0; dt < 4; dt++)
          acc[tt][dt] = MFMA16(vf[dt][ct], pfr, acc[tt][dt]);
        accl[tt] = MFMA16(ones4, pfr, accl[tt]);
      }
    }
  }
  // --- epilogue: lane owns col=qrow=c; rows are channels -> 8B stores ---
  int n = nh >> 2, h = nh & 3;
#pragma unroll
  for (int tt = 0; tt < 2; tt++) {
    float linv = 1.0f / accl[tt][0];  // all regs identical; lane's own column
    short* dst = (short*)ot + ((size_t)n * 1600 + l0 + tt * 16 + c) * 256 + h * 64;
#pragma unroll
    for (int dt = 0; dt < 4; dt++) {
      us4 pk;
#pragma unroll
      for (int r = 0; r < 4; r++) pk[r] = f2bf_bits(acc[tt][dt][r] * linv);
      *(us4*)(dst + dt * 16 + quad * 4) = pk;
    }
  }
}

// ---------------------------------------------------------------------------
// K3: (1,9) conv as MFMA GEMM (unchanged from round 10).
// ---------------------------------------------------------------------------
__global__ void k_conv9(const bf16* __restrict__ ot, const bf16* __restrict__ Wt,
                        const float* __restrict__ bo, const float* __restrict__ g1,
                        const float* __restrict__ be1, const float* __restrict__ mu1,
                        const float* __restrict__ va1, const float* __restrict__ x,
                        bf16* __restrict__ y, bf16* __restrict__ yt) {
  __shared__ short tl[2][16 * 66];
  int wv = threadIdx.x >> 6;
  int lane = threadIdx.x & 63;
  int quad = lane >> 4, c = lane & 15;
  int n = blockIdx.y;
  int l0 = blockIdx.x * 32 + wv * 16;
  int la = l0 + c;
  int va = la % 25;
  const short* obase = (const short*)ot + (size_t)n * 409600;
  const short* wbase = (const short*)Wt;
  f32x4 acc[4] = {};
  for (int r = 0; r < 9; r++) {
    int sh = r - 4;
    bool valid = (unsigned)(va + sh) < 25u;
    int lp = la + sh;
    lp = max(0, min(1599, lp));
    const short* arow = obase + (size_t)lp * 256 + quad * 8;
    const short* wrow = wbase + (size_t)r * 8 * 4 * 64 * 8 + lane * 8;
    short8 z8 = {0, 0, 0, 0, 0, 0, 0, 0};
#pragma unroll 4
    for (int kc = 0; kc < 8; kc++) {
      short8 af = *(const short8*)(arow + kc * 32);
      af = valid ? af : z8;
      const short* wk = wrow + kc * 4 * 64 * 8;
      short8 b0 = *(const short8*)(wk);
      short8 b1 = *(const short8*)(wk + 512);
      short8 b2 = *(const short8*)(wk + 1024);
      short8 b3 = *(const short8*)(wk + 1536);
      acc[0] = __builtin_amdgcn_mfma_f32_16x16x32_bf16(af, b0, acc[0], 0, 0, 0);
      acc[1] = __builtin_amdgcn_mfma_f32_16x16x32_bf16(af, b1, acc[1], 0, 0, 0);
      acc[2] = __builtin_amdgcn_mfma_f32_16x16x32_bf16(af, b2, acc[2], 0, 0, 0);
      acc[3] = __builtin_amdgcn_mfma_f32_16x16x32_bf16(af, b3, acc[3], 0, 0, 0);
    }
  }
  short* tlw = &tl[wv][0];
  float outv[4][4];
#pragma unroll
  for (int cot = 0; cot < 4; cot++) {
    int co = cot * 16 + c;
    float inv = g1[co] * rsqrtf(va1[co] + 1e-5f);
    float add = be1[co] - mu1[co] * inv + bo[co] * inv;
    f32x4 xr = *(const f32x4*)(x + (size_t)(n * 64 + co) * 1600 + l0 + quad * 4);
    us4 yb;
#pragma unroll
    for (int rr = 0; rr < 4; rr++) {
      float vv = fmaxf(acc[cot][rr] * inv + add + xr[rr], 0.f);
      outv[cot][rr] = vv;
      yb[rr] = f2bf_bits(vv);
    }
    *(us4*)((short*)y + (size_t)(n * 64 + co) * 1600 + l0 + quad * 4) = yb;
  }
  asm volatile("" ::: "memory");
  bool ev = (c & 1) == 0;
#pragma unroll
  for (int cot = 0; cot < 4; cot++) {
    int us_[4];
#pragma unroll
    for (int rr = 0; rr < 4; rr++) us_[rr] = f2bf_bits(outv[cot][rr]);
    int xv0 = dppx1i(us_[0]);
    int xv1 = dppx1i(us_[1]);
    int xv2 = dppx1i(us_[2]);
    int xv3 = dppx1i(us_[3]);
    if (ev) {
      *(int*)(tlw + (quad * 4 + 0) * 66 + cot * 16 + c) = (xv0 << 16) | us_[0];
      *(int*)(tlw + (quad * 4 + 1) * 66 + cot * 16 + c) = (xv1 << 16) | us_[1];
    } else {
      *(int*)(tlw + (quad * 4 + 2) * 66 + cot * 16 + (c - 1)) = (us_[2] << 16) | xv2;
      *(int*)(tlw + (quad * 4 + 3) * 66 + cot * 16 + (c - 1)) = (us_[3] << 16) | xv3;
    }
  }
  asm volatile("" ::: "memory");
  int row = lane >> 2, seg = lane & 3;
  short8 y0 = *(const short8*)(tlw + row * 66 + seg * 16);
  short8 y1 = *(const short8*)(tlw + row * 66 + seg * 16 + 8);
  short* yd = (short*)yt + ((size_t)n * 1600 + l0 + row) * 64 + seg * 16;
  *(short8*)(yd) = y0;
  *(short8*)(yd + 8) = y1;
}

// ---------------------------------------------------------------------------
// K4: 1x1 conv as MFMA GEMM (unchanged).
// ---------------------------------------------------------------------------
__global__ void k_ff(const bf16* __restrict__ yt, const bf16* __restrict__ WfT,
                     const bf16* __restrict__ y, const float* __restrict__ bff,
                     const float* __restrict__ g2, const float* __restrict__ be2,
                     const float* __restrict__ mu2, const float* __restrict__ va2,
                     float* __restrict__ out) {
  int wv = threadIdx.x >> 6;
  int lane = threadIdx.x & 63;
  int quad = lane >> 4, c = lane & 15;
  int n = blockIdx.y;
  int l0 = blockIdx.x * 32 + wv * 16;
  const short* arow = (const short*)yt + ((size_t)n * 1600 + l0 + c) * 64 + quad * 8;
  const short* wbase = (const short*)WfT + lane * 8;
  f32x4 acc[4] = {};
#pragma unroll
  for (int kc = 0; kc < 2; kc++) {
    short8 af = *(const short8*)(arow + kc * 32);
    const short* wk = wbase + kc * 2048;
    short8 b0 = *(const short8*)(wk);
    short8 b1 = *(const short8*)(wk + 512);
    short8 b2 = *(const short8*)(wk + 1024);
    short8 b3 = *(const short8*)(wk + 1536);
    acc[0] = __builtin_amdgcn_mfma_f32_16x16x32_bf16(af, b0, acc[0], 0, 0, 0);
    acc[1] = __builtin_amdgcn_mfma_f32_16x16x32_bf16(af, b1, acc[1], 0, 0, 0);
    acc[2] = __builtin_amdgcn_mfma_f32_16x16x32_bf16(af, b2, acc[2], 0, 0, 0);
    acc[3] = __builtin_amdgcn_mfma_f32_16x16x32_bf16(af, b3, acc[3], 0, 0, 0);
  }
#pragma unroll
  for (int cot = 0; cot < 4; cot++) {
    int co = cot * 16 + c;
    float inv = g2[co] * rsqrtf(va2[co] + 1e-5f);
    float add = be2[co] - mu2[co] * inv + bff[co] * inv;
    size_t base = (size_t)(n * 64 + co) * 1600 + l0 + quad * 4;
    us4 yr = *(const us4*)((const short*)y + base);
    f32x4 ov;
#pragma unroll
    for (int rr = 0; rr < 4; rr++) {
      unsigned short ub = yr[rr];
      float yv;
      *(unsigned*)&yv = ((unsigned)ub) << 16;  // bf16 bits -> f32
      ov[rr] = fmaxf(acc[cot][rr] * inv + add + yv, 0.f);
    }
    *(f32x4*)(out + base) = ov;
  }
}

extern "C" void kernel_launch(void* const* d_in, const int* in_sizes, int n_in,
                              void* d_out, int out_size, void* d_ws, size_t ws_size,
                              hipStream_t stream) {
  const float* x   = (const float*)d_in[0];
  const float* Wq  = (const float*)d_in[1];
  const float* bq  = (const float*)d_in[2];
  const float* Wo  = (const float*)d_in[3];
  const float* bo  = (const float*)d_in[4];
  const float* g1  = (const float*)d_in[5];
  const float* be1 = (const float*)d_in[6];
  const float* mu1 = (const float*)d_in[7];
  const float* va1 = (const float*)d_in[8];
  const float* Wf  = (const float*)d_in[9];
  const float* bff = (const float*)d_in[10];
  const float* g2  = (const float*)d_in[11];
  const float* be2 = (const float*)d_in[12];
  const float* mu2 = (const float*)d_in[13];
  const float* va2 = (const float*)d_in[14];

  // ws (bf16 elems): q,k [nh][l][64]; vt [nh][64][l]; ot [n][l][256];
  //                  y [n][64][l]; yt [n][l][64]; Wt; WfT; WqT   (~46.6MB)
  const size_t QKV = (size_t)64 * 1600 * 64;
  bf16* qw  = (bf16*)d_ws;
  bf16* kw  = qw + QKV;
  bf16* vtw = kw + QKV;
  bf16* otw = vtw + QKV;
  bf16* yw  = otw + QKV;
  bf16* ytw = yw + 1638400;
  bf16* Wt  = ytw + 1638400;
  bf16* WfT = Wt + 147456;
  bf16* WqT = WfT + 4096;

  k_prep<<<576, 256, 0, stream>>>(Wo, Wf, Wq, Wt, WfT, WqT);
  k_qkv<<<1600, 64, 0, stream>>>(x, WqT, bq, qw, kw, vtw);
  k_attn<<<1600, 128, 0, stream>>>(qw, kw, vtw, otw);
  dim3 gc(50, 16);
  k_conv9<<<gc, 128, 0, stream>>>(otw, Wt, bo, g1, be1, mu1, va1, x, yw, ytw);
  k_ff<<<gc, 128, 0, stream>>>(ytw, WfT, yw, bff, g2, be2, mu2, va2, (float*)d_out);
}

// Round 14
// 264.007 us; speedup vs baseline: 1.3228x; 1.3228x over previous
//
#include <hip/hip_runtime.h>
#include <hip/hip_bf16.h>

// Problem constants (fixed by setup_inputs)
#define NB 16     // batch
#define CC 64     // channels
#define TT 64
#define VV 25
#define LL 1600   // T*V
#define HH 4
#define DD 64
#define NH 64     // N*H

// Dtype contract (established rounds 0-3): d_in fp32, d_out fp32,
// tolerance bf16-grade (2% * max|ref|) -> internal bf16 pipeline OK.
// Round-13 lesson: mfma_16x16x16 costs the same cycles as 16x16x32 on gfx950
// -> always use the largest-K shape. k_attn reverted to round-10 structure
// (123 us proven) + split-KV parallelism + v_perm pack.

typedef __hip_bfloat16 bf16;
typedef __attribute__((ext_vector_type(8))) short short8;
typedef __attribute__((ext_vector_type(4))) float f32x4;
typedef __attribute__((ext_vector_type(4))) unsigned short us4;

__device__ __forceinline__ float b2f(bf16 v) { return __bfloat162float(v); }
__device__ __forceinline__ unsigned short f2bf_bits(float f) {
  bf16 h = __float2bfloat16(f);
  return *(unsigned short*)&h;
}
// pack two f32 -> bf16x2 by truncation: one v_perm_b32 (validated round 13)
__device__ __forceinline__ unsigned pkbf_trunc(float lo, float hi) {
  return __builtin_amdgcn_perm(__float_as_uint(hi), __float_as_uint(lo), 0x07060302u);
}
// xor-1 lane exchange via DPP quad_perm [1,0,3,2] (0xB1): VALU, not LDS.
__device__ __forceinline__ float dppx1(float x) {
  return __int_as_float(
      __builtin_amdgcn_mov_dpp(__float_as_int(x), 0xB1, 0xF, 0xF, true));
}
__device__ __forceinline__ int dppx1i(int x) {
  return __builtin_amdgcn_mov_dpp(x, 0xB1, 0xF, 0xF, true);
}

// ---------------------------------------------------------------------------
// K0: weight prep (unchanged).
// ---------------------------------------------------------------------------
__global__ void k_prep(const float* __restrict__ Wo, const float* __restrict__ Wf,
                       const float* __restrict__ Wq,
                       bf16* __restrict__ Wt, bf16* __restrict__ WfT,
                       bf16* __restrict__ WqT) {
  int i = blockIdx.x * 256 + threadIdx.x;
  if (i < 147456) {
    int j = i & 7, lane = (i >> 3) & 63, cot = (i >> 9) & 3;
    int kc = (i >> 11) & 7, r = i >> 14;
    int co = cot * 16 + (lane & 15);
    int ci = kc * 32 + (lane >> 4) * 8 + j;
    Wt[i] = __float2bfloat16(Wo[(co * 256 + ci) * 9 + r]);
  }
  if (i < 4096) {
    int j = i & 7, lane = (i >> 3) & 63, cot = (i >> 9) & 3, kc = (i >> 11) & 1;
    int co = cot * 16 + (lane & 15);
    int ci = kc * 32 + (lane >> 4) * 8 + j;
    WfT[i] = __float2bfloat16(Wf[co * 64 + ci]);
  }
  if (i < 49152) {
    int jj = i & 7, lane = (i >> 3) & 63, g = i >> 9;  // g 0..95
    int nt = g % 48, half = g / 48;
    int ch = half * 32 + (lane >> 4) * 8 + jj;
    int j = nt * 16 + (lane & 15);
    WqT[i] = __float2bfloat16(Wq[ch * 768 + j]);
  }
}

// ---------------------------------------------------------------------------
// K1: qkv projection as MFMA GEMM (unchanged from round 10).
// ---------------------------------------------------------------------------
__global__ __launch_bounds__(64)
void k_qkv(const float* __restrict__ x, const bf16* __restrict__ WqT,
           const float* __restrict__ bq,
           bf16* __restrict__ q, bf16* __restrict__ k, bf16* __restrict__ vt) {
  __shared__ short xa[16 * 72];  // A-tile [16 l][64 c] (+pad)
  __shared__ short tr[16 * 66];  // transpose buffer for q/k epilogue
  int lane = threadIdx.x;
  int quad = lane >> 4, c = lane & 15;
  int n = blockIdx.x / 100;
  int l0 = (blockIdx.x % 100) * 16;
  bool ev = (c & 1) == 0;

  {
    int l = c;
    const float* xb = x + (size_t)n * 102400 + (size_t)(quad * 16) * 1600 + l0 + l;
    unsigned short vb[16];
#pragma unroll
    for (int i = 0; i < 16; i++) vb[i] = f2bf_bits(xb[(size_t)i * 1600]);
    unsigned wrds[8];
#pragma unroll
    for (int i = 0; i < 8; i++)
      wrds[i] = ((unsigned)vb[2 * i + 1] << 16) | vb[2 * i];
    *(short8*)(xa + l * 72 + quad * 16) = *(short8*)&wrds[0];
    *(short8*)(xa + l * 72 + quad * 16 + 8) = *(short8*)&wrds[4];
  }
  asm volatile("" ::: "memory");
  short8 af0 = *(const short8*)(xa + c * 72 + quad * 8);
  short8 af1 = *(const short8*)(xa + c * 72 + 32 + quad * 8);

  const short* wq0 = (const short*)WqT;
  const float QSCALE = 0.125f * 1.44269504f;

#pragma unroll
  for (int s = 0; s < 2; s++) {
#pragma unroll
    for (int h = 0; h < 4; h++) {
      asm volatile("" ::: "memory");
#pragma unroll
      for (int t = 0; t < 4; t++) {
        int nt = s * 16 + h * 4 + t;
        float bv = bq[nt * 16 + c];
        f32x4 z = {bv, bv, bv, bv};
        short8 b0 = *(const short8*)(wq0 + ((size_t)nt * 64 + lane) * 8);
        short8 b1 = *(const short8*)(wq0 + ((size_t)(48 + nt) * 64 + lane) * 8);
        z = __builtin_amdgcn_mfma_f32_16x16x32_bf16(af0, b0, z, 0, 0, 0);
        z = __builtin_amdgcn_mfma_f32_16x16x32_bf16(af1, b1, z, 0, 0, 0);
        if (s == 0) {
#pragma unroll
          for (int r = 0; r < 4; r++) z[r] *= QSCALE;
        }
        int us_[4];
#pragma unroll
        for (int r = 0; r < 4; r++) us_[r] = f2bf_bits(z[r]);
        int xv0 = dppx1i(us_[0]);
        int xv1 = dppx1i(us_[1]);
        int xv2 = dppx1i(us_[2]);
        int xv3 = dppx1i(us_[3]);
        if (ev) {
          *(int*)(tr + (quad * 4 + 0) * 66 + t * 16 + c) = (xv0 << 16) | us_[0];
          *(int*)(tr + (quad * 4 + 1) * 66 + t * 16 + c) = (xv1 << 16) | us_[1];
        } else {
          *(int*)(tr + (quad * 4 + 2) * 66 + t * 16 + (c - 1)) = (us_[2] << 16) | xv2;
          *(int*)(tr + (quad * 4 + 3) * 66 + t * 16 + (c - 1)) = (us_[3] << 16) | xv3;
        }
      }
      asm volatile("" ::: "memory");
      int row = lane >> 2, seg = lane & 3;
      short8 o0 = *(const short8*)(tr + row * 66 + seg * 16);
      short8 o1 = *(const short8*)(tr + row * 66 + seg * 16 + 8);
      short* dstp = (short*)(s == 0 ? q : k);
      short* dst = dstp + ((size_t)(n * 4 + h) * 1600 + l0 + row) * 64 + seg * 16;
      *(short8*)(dst) = o0;
      *(short8*)(dst + 8) = o1;
    }
  }
#pragma unroll
  for (int h = 0; h < 4; h++) {
#pragma unroll
    for (int t = 0; t < 4; t++) {
      int nt = 32 + h * 4 + t;
      float bv = bq[nt * 16 + c];
      f32x4 z = {bv, bv, bv, bv};
      short8 b0 = *(const short8*)(wq0 + ((size_t)nt * 64 + lane) * 8);
      short8 b1 = *(const short8*)(wq0 + ((size_t)(48 + nt) * 64 + lane) * 8);
      z = __builtin_amdgcn_mfma_f32_16x16x32_bf16(af0, b0, z, 0, 0, 0);
      z = __builtin_amdgcn_mfma_f32_16x16x32_bf16(af1, b1, z, 0, 0, 0);
      us4 pk;
#pragma unroll
      for (int r = 0; r < 4; r++) pk[r] = f2bf_bits(z[r]);
      *(us4*)((short*)vt + ((size_t)((n * 4 + h) * 64 + t * 16 + c)) * 1600 +
              l0 + quad * 4) = pk;
    }
  }
}

// ---------------------------------------------------------------------------
// K2: MFMA flash attention = round-10 structure (123 us proven: normal
// orientation, K tile LDS-staged w/ 1-iter prefetch, XCD swizzle, fixed-max
// exp2(s-8) with bias folded into MFMA C-init) + two round-14 deltas:
//  (a) split-KV: fixed-max partials share one scale -> plain-sum combine.
//      split==2: 2 blocks per (nh,qt), kt ranges [0,13)/[13,25); raw sums +
//      per-row l partials to ws; k_comb normalizes. Doubles concurrency
//      (occupancy 15% was the limiter). split==1 fallback = round-10 exact.
//  (b) P-transpose pack via v_perm (pkbf_trunc): cvt+shl+or -> 1 op.
// grid split*1600, block 128 (2 waves x 32 Q-rows).
// ---------------------------------------------------------------------------
__global__ __launch_bounds__(128, 2)
void k_attn(const bf16* __restrict__ q, const bf16* __restrict__ k,
            const bf16* __restrict__ vt, bf16* __restrict__ po,
            float* __restrict__ ls, int split) {
  __shared__ short kbuf[64 * 72];    // K tile, padded rows
  __shared__ short pl_all[2][2304];  // per wave: 2 tiles of [16 m][72 j]
  int tid = threadIdx.x;
  int wv = tid >> 6, lane = tid & 63;
  int quad = lane >> 4, c = lane & 15;
  int bid = blockIdx.x;
  int xcd = bid & 7;
  int slot = bid >> 3;
  int half, qt, grp;
  if (split == 2) { half = slot & 1; qt = (slot >> 1) % 25; grp = slot / 50; }
  else            { half = 0;        qt = slot % 25;        grp = slot / 25; }
  int nh = grp * 8 + xcd;          // nh%8 == bid%8 -> per-XCD K/V stream
  int kt0 = half ? 13 : 0;
  int kt1 = (split == 2 && half == 0) ? 13 : 25;
  int l0 = qt * 64 + wv * 32;      // wave's rows: tiles at l0, l0+16
  short* pl = pl_all[wv];

  const short* qbase = (const short*)q + ((size_t)nh * 1600 + l0 + c) * 64 + quad * 8;
  short8 qf[2][2];
  qf[0][0] = *(const short8*)(qbase);
  qf[0][1] = *(const short8*)(qbase + 32);
  qf[1][0] = *(const short8*)(qbase + 16 * 64);
  qf[1][1] = *(const short8*)(qbase + 16 * 64 + 32);

  short ob = (c == 0) ? (short)0x3F80 : (short)0;  // bf16 1.0 in col 0
  short8 onesf = {ob, ob, ob, ob, ob, ob, ob, ob};

  f32x4 acc[2][5] = {};  // per tile: 4 d-tiles + l-tile (ones-trick)

  const short* kg = (const short*)k + (size_t)nh * 102400;
  const short* vg = (const short*)vt + (size_t)nh * 102400;
  bool ev = (c & 1) == 0;
  int cbase = c & ~1;

  // prologue: staging loads for kt0
  short8 sk[4];
  {
    const short8* gk = (const short8*)(kg + kt0 * 4096);
#pragma unroll
    for (int i = 0; i < 4; i++) sk[i] = gk[tid + i * 128];
  }

  for (int kt = kt0; kt < kt1; kt++) {
    __syncthreads();  // kbuf reads of previous iter done
#pragma unroll
    for (int i = 0; i < 4; i++) {
      int ch = tid + i * 128;
      *(short8*)(kbuf + (ch >> 3) * 72 + (ch & 7) * 8) = sk[i];
    }
    __syncthreads();  // kbuf(kt) visible
    // --- V frags: issued FIRST, drain under QK+exp2+pack ---
    short8 vf[4][2];
#pragma unroll
    for (int ct = 0; ct < 4; ct++) {
      const short* p0 = vg + (size_t)(ct * 16 + c) * 1600 + kt * 64 + quad * 8;
      vf[ct][0] = *(const short8*)(p0);
      vf[ct][1] = *(const short8*)(p0 + 32);
    }
    if (kt + 1 < kt1) {  // K staging loads for kt+1
      const short8* gk = (const short8*)(kg + (kt + 1) * 4096);
#pragma unroll
      for (int i = 0; i < 4; i++) sk[i] = gk[tid + i * 128];
    }
    // --- K frags from LDS + QK MFMAs (C init = -8 folds softmax bias) ---
    f32x4 s[2][4];
#pragma unroll
    for (int ct = 0; ct < 4; ct++) {
      short8 kf0 = *(const short8*)(kbuf + (ct * 16 + c) * 72 + quad * 8);
      short8 kf1 = *(const short8*)(kbuf + (ct * 16 + c) * 72 + 32 + quad * 8);
      f32x4 z0 = {-8.f, -8.f, -8.f, -8.f}, z1 = {-8.f, -8.f, -8.f, -8.f};
      z0 = __builtin_amdgcn_mfma_f32_16x16x32_bf16(qf[0][0], kf0, z0, 0, 0, 0);
      z0 = __builtin_amdgcn_mfma_f32_16x16x32_bf16(qf[0][1], kf1, z0, 0, 0, 0);
      z1 = __builtin_amdgcn_mfma_f32_16x16x32_bf16(qf[1][0], kf0, z1, 0, 0, 0);
      z1 = __builtin_amdgcn_mfma_f32_16x16x32_bf16(qf[1][1], kf1, z1, 0, 0, 0);
      s[0][ct] = z0;
      s[1][ct] = z1;
    }
    // --- p = exp2(s), both tiles ---
#pragma unroll
    for (int tt = 0; tt < 2; tt++)
#pragma unroll
      for (int ct = 0; ct < 4; ct++)
#pragma unroll
        for (int r = 0; r < 4; r++) s[tt][ct][r] = exp2f(s[tt][ct][r]);
    // --- P: C-layout -> A-layout LDS (wave-private, DPP + v_perm pack) ---
    asm volatile("" ::: "memory");
#pragma unroll
    for (int tt = 0; tt < 2; tt++) {
      short* plt = pl + tt * 1152;
#pragma unroll
      for (int ct = 0; ct < 4; ct++) {
        float x0 = dppx1(s[tt][ct][0]);
        float x1 = dppx1(s[tt][ct][1]);
        float x2 = dppx1(s[tt][ct][2]);
        float x3 = dppx1(s[tt][ct][3]);
        float lo0 = ev ? s[tt][ct][0] : x2;
        float hi0 = ev ? x0 : s[tt][ct][2];
        float lo1 = ev ? s[tt][ct][1] : x3;
        float hi1 = ev ? x1 : s[tt][ct][3];
        int r0 = ev ? 0 : 2, r1 = ev ? 1 : 3;
        unsigned w0 = pkbf_trunc(lo0, hi0);
        unsigned w1 = pkbf_trunc(lo1, hi1);
        *(unsigned*)(plt + (quad * 4 + r0) * 72 + ct * 16 + cbase) = w0;
        *(unsigned*)(plt + (quad * 4 + r1) * 72 + ct * 16 + cbase) = w1;
      }
    }
    asm volatile("" ::: "memory");
    short8 pf[2][2];
#pragma unroll
    for (int tt = 0; tt < 2; tt++) {
      pf[tt][0] = *(const short8*)(pl + tt * 1152 + c * 72 + quad * 8);
      pf[tt][1] = *(const short8*)(pl + tt * 1152 + c * 72 + 32 + quad * 8);
    }
    // --- PV + l accumulate ---
#pragma unroll
    for (int ct = 0; ct < 4; ct++) {
#pragma unroll
      for (int tt = 0; tt < 2; tt++) {
        acc[tt][ct] = __builtin_amdgcn_mfma_f32_16x16x32_bf16(pf[tt][0], vf[ct][0], acc[tt][ct], 0, 0, 0);
        acc[tt][ct] = __builtin_amdgcn_mfma_f32_16x16x32_bf16(pf[tt][1], vf[ct][1], acc[tt][ct], 0, 0, 0);
      }
    }
#pragma unroll
    for (int tt = 0; tt < 2; tt++) {
      acc[tt][4] = __builtin_amdgcn_mfma_f32_16x16x32_bf16(pf[tt][0], onesf, acc[tt][4], 0, 0, 0);
      acc[tt][4] = __builtin_amdgcn_mfma_f32_16x16x32_bf16(pf[tt][1], onesf, acc[tt][4], 0, 0, 0);
    }
  }
  // --- epilogue: transpose via pl, coalesced stores. split2 = raw sums +
  //     per-row l partials; split1 = divide in epilogue (round-10 exact) ---
  int n = nh >> 2, h = nh & 3;
#pragma unroll
  for (int tt = 0; tt < 2; tt++) {
    float linv[4] = {1.f, 1.f, 1.f, 1.f};
    if (split == 1) {
#pragma unroll
      for (int r = 0; r < 4; r++)
        linv[r] = 1.0f / __shfl(acc[tt][4][r], lane & 48);
    }
    asm volatile("" ::: "memory");
#pragma unroll
    for (int t = 0; t < 4; t++) {
      int us_[4];
#pragma unroll
      for (int r = 0; r < 4; r++) us_[r] = f2bf_bits(acc[tt][t][r] * linv[r]);
      int xv0 = dppx1i(us_[0]);
      int xv1 = dppx1i(us_[1]);
      int xv2 = dppx1i(us_[2]);
      int xv3 = dppx1i(us_[3]);
      if (ev) {
        *(int*)(pl + (quad * 4 + 0) * 66 + t * 16 + c) = (xv0 << 16) | us_[0];
        *(int*)(pl + (quad * 4 + 1) * 66 + t * 16 + c) = (xv1 << 16) | us_[1];
      } else {
        *(int*)(pl + (quad * 4 + 2) * 66 + t * 16 + (c - 1)) = (us_[2] << 16) | xv2;
        *(int*)(pl + (quad * 4 + 3) * 66 + t * 16 + (c - 1)) = (us_[3] << 16) | xv3;
      }
    }
    asm volatile("" ::: "memory");
    int row = lane >> 2, seg = lane & 3;
    short8 o0 = *(const short8*)(pl + row * 66 + seg * 16);
    short8 o1 = *(const short8*)(pl + row * 66 + seg * 16 + 8);
    short* dst = (short*)po + (size_t)half * 6553600 +
                 ((size_t)n * 1600 + l0 + tt * 16 + row) * 256 + h * 64 + seg * 16;
    *(short8*)(dst) = o0;
    *(short8*)(dst + 8) = o1;
    if (split == 2 && c == 0) {
#pragma unroll
      for (int r = 0; r < 4; r++)
        ls[half * 102400 + nh * 1600 + l0 + tt * 16 + quad * 4 + r] = acc[tt][4][r];
    }
    asm volatile("" ::: "memory");  // pl reused by next tile
  }
}

// ---------------------------------------------------------------------------
// K2b: combine split-KV partials: ot = (po0 + po1) / (l0 + l1). In-place into
// the po0 half (each thread reads both halves before writing). grid 3200x256.
// ---------------------------------------------------------------------------
__global__ void k_comb(const bf16* po_in, const float* __restrict__ ls, bf16* ot) {
  int i = blockIdx.x * 256 + threadIdx.x;  // 819200 threads, 8 ch each
  int ch8 = i & 31;
  int rest = i >> 5;                       // n*1600 + l
  int l = rest % 1600;
  int n = rest / 1600;
  int nh = n * 4 + (ch8 >> 3);
  float inv = 1.0f / (ls[nh * 1600 + l] + ls[102400 + nh * 1600 + l]);
  const short* a = (const short*)po_in + (size_t)rest * 256 + ch8 * 8;
  short8 av = *(const short8*)a;
  short8 bv = *(const short8*)(a + 6553600);
  unsigned short o8[8];
#pragma unroll
  for (int j = 0; j < 8; j++) {
    float fa = __uint_as_float(((unsigned)(unsigned short)av[j]) << 16);
    float fb = __uint_as_float(((unsigned)(unsigned short)bv[j]) << 16);
    o8[j] = f2bf_bits((fa + fb) * inv);
  }
  *(short8*)((short*)ot + (size_t)rest * 256 + ch8 * 8) = *(short8*)o8;
}

// ---------------------------------------------------------------------------
// K3: (1,9) conv as MFMA GEMM (unchanged).
// ---------------------------------------------------------------------------
__global__ void k_conv9(const bf16* __restrict__ ot, const bf16* __restrict__ Wt,
                        const float* __restrict__ bo, const float* __restrict__ g1,
                        const float* __restrict__ be1, const float* __restrict__ mu1,
                        const float* __restrict__ va1, const float* __restrict__ x,
                        bf16* __restrict__ y, bf16* __restrict__ yt) {
  __shared__ short tl[2][16 * 66];
  int wv = threadIdx.x >> 6;
  int lane = threadIdx.x & 63;
  int quad = lane >> 4, c = lane & 15;
  int n = blockIdx.y;
  int l0 = blockIdx.x * 32 + wv * 16;
  int la = l0 + c;
  int va = la % 25;
  const short* obase = (const short*)ot + (size_t)n * 409600;
  const short* wbase = (const short*)Wt;
  f32x4 acc[4] = {};
  for (int r = 0; r < 9; r++) {
    int sh = r - 4;
    bool valid = (unsigned)(va + sh) < 25u;
    int lp = la + sh;
    lp = max(0, min(1599, lp));
    const short* arow = obase + (size_t)lp * 256 + quad * 8;
    const short* wrow = wbase + (size_t)r * 8 * 4 * 64 * 8 + lane * 8;
    short8 z8 = {0, 0, 0, 0, 0, 0, 0, 0};
#pragma unroll 4
    for (int kc = 0; kc < 8; kc++) {
      short8 af = *(const short8*)(arow + kc * 32);
      af = valid ? af : z8;
      const short* wk = wrow + kc * 4 * 64 * 8;
      short8 b0 = *(const short8*)(wk);
      short8 b1 = *(const short8*)(wk + 512);
      short8 b2 = *(const short8*)(wk + 1024);
      short8 b3 = *(const short8*)(wk + 1536);
      acc[0] = __builtin_amdgcn_mfma_f32_16x16x32_bf16(af, b0, acc[0], 0, 0, 0);
      acc[1] = __builtin_amdgcn_mfma_f32_16x16x32_bf16(af, b1, acc[1], 0, 0, 0);
      acc[2] = __builtin_amdgcn_mfma_f32_16x16x32_bf16(af, b2, acc[2], 0, 0, 0);
      acc[3] = __builtin_amdgcn_mfma_f32_16x16x32_bf16(af, b3, acc[3], 0, 0, 0);
    }
  }
  short* tlw = &tl[wv][0];
  float outv[4][4];
#pragma unroll
  for (int cot = 0; cot < 4; cot++) {
    int co = cot * 16 + c;
    float inv = g1[co] * rsqrtf(va1[co] + 1e-5f);
    float add = be1[co] - mu1[co] * inv + bo[co] * inv;
    f32x4 xr = *(const f32x4*)(x + (size_t)(n * 64 + co) * 1600 + l0 + quad * 4);
    us4 yb;
#pragma unroll
    for (int rr = 0; rr < 4; rr++) {
      float vv = fmaxf(acc[cot][rr] * inv + add + xr[rr], 0.f);
      outv[cot][rr] = vv;
      yb[rr] = f2bf_bits(vv);
    }
    *(us4*)((short*)y + (size_t)(n * 64 + co) * 1600 + l0 + quad * 4) = yb;
  }
  asm volatile("" ::: "memory");
  bool ev = (c & 1) == 0;
#pragma unroll
  for (int cot = 0; cot < 4; cot++) {
    int us_[4];
#pragma unroll
    for (int rr = 0; rr < 4; rr++) us_[rr] = f2bf_bits(outv[cot][rr]);
    int xv0 = dppx1i(us_[0]);
    int xv1 = dppx1i(us_[1]);
    int xv2 = dppx1i(us_[2]);
    int xv3 = dppx1i(us_[3]);
    if (ev) {
      *(int*)(tlw + (quad * 4 + 0) * 66 + cot * 16 + c) = (xv0 << 16) | us_[0];
      *(int*)(tlw + (quad * 4 + 1) * 66 + cot * 16 + c) = (xv1 << 16) | us_[1];
    } else {
      *(int*)(tlw + (quad * 4 + 2) * 66 + cot * 16 + (c - 1)) = (us_[2] << 16) | xv2;
      *(int*)(tlw + (quad * 4 + 3) * 66 + cot * 16 + (c - 1)) = (us_[3] << 16) | xv3;
    }
  }
  asm volatile("" ::: "memory");
  int row = lane >> 2, seg = lane & 3;
  short8 y0 = *(const short8*)(tlw + row * 66 + seg * 16);
  short8 y1 = *(const short8*)(tlw + row * 66 + seg * 16 + 8);
  short* yd = (short*)yt + ((size_t)n * 1600 + l0 + row) * 64 + seg * 16;
  *(short8*)(yd) = y0;
  *(short8*)(yd + 8) = y1;
}

// ---------------------------------------------------------------------------
// K4: 1x1 conv as MFMA GEMM (unchanged).
// ---------------------------------------------------------------------------
__global__ void k_ff(const bf16* __restrict__ yt, const bf16* __restrict__ WfT,
                     const bf16* __restrict__ y, const float* __restrict__ bff,
                     const float* __restrict__ g2, const float* __restrict__ be2,
                     const float* __restrict__ mu2, const float* __restrict__ va2,
                     float* __restrict__ out) {
  int wv = threadIdx.x >> 6;
  int lane = threadIdx.x & 63;
  int quad = lane >> 4, c = lane & 15;
  int n = blockIdx.y;
  int l0 = blockIdx.x * 32 + wv * 16;
  const short* arow = (const short*)yt + ((size_t)n * 1600 + l0 + c) * 64 + quad * 8;
  const short* wbase = (const short*)WfT + lane * 8;
  f32x4 acc[4] = {};
#pragma unroll
  for (int kc = 0; kc < 2; kc++) {
    short8 af = *(const short8*)(arow + kc * 32);
    const short* wk = wbase + kc * 2048;
    short8 b0 = *(const short8*)(wk);
    short8 b1 = *(const short8*)(wk + 512);
    short8 b2 = *(const short8*)(wk + 1024);
    short8 b3 = *(const short8*)(wk + 1536);
    acc[0] = __builtin_amdgcn_mfma_f32_16x16x32_bf16(af, b0, acc[0], 0, 0, 0);
    acc[1] = __builtin_amdgcn_mfma_f32_16x16x32_bf16(af, b1, acc[1], 0, 0, 0);
    acc[2] = __builtin_amdgcn_mfma_f32_16x16x32_bf16(af, b2, acc[2], 0, 0, 0);
    acc[3] = __builtin_amdgcn_mfma_f32_16x16x32_bf16(af, b3, acc[3], 0, 0, 0);
  }
#pragma unroll
  for (int cot = 0; cot < 4; cot++) {
    int co = cot * 16 + c;
    float inv = g2[co] * rsqrtf(va2[co] + 1e-5f);
    float add = be2[co] - mu2[co] * inv + bff[co] * inv;
    size_t base = (size_t)(n * 64 + co) * 1600 + l0 + quad * 4;
    us4 yr = *(const us4*)((const short*)y + base);
    f32x4 ov;
#pragma unroll
    for (int rr = 0; rr < 4; rr++) {
      unsigned short ub = yr[rr];
      float yv;
      *(unsigned*)&yv = ((unsigned)ub) << 16;  // bf16 bits -> f32
      ov[rr] = fmaxf(acc[cot][rr] * inv + add + yv, 0.f);
    }
    *(f32x4*)(out + base) = ov;
  }
}

extern "C" void kernel_launch(void* const* d_in, const int* in_sizes, int n_in,
                              void* d_out, int out_size, void* d_ws, size_t ws_size,
                              hipStream_t stream) {
  const float* x   = (const float*)d_in[0];
  const float* Wq  = (const float*)d_in[1];
  const float* bq  = (const float*)d_in[2];
  const float* Wo  = (const float*)d_in[3];
  const float* bo  = (const float*)d_in[4];
  const float* g1  = (const float*)d_in[5];
  const float* be1 = (const float*)d_in[6];
  const float* mu1 = (const float*)d_in[7];
  const float* va1 = (const float*)d_in[8];
  const float* Wf  = (const float*)d_in[9];
  const float* bff = (const float*)d_in[10];
  const float* g2  = (const float*)d_in[11];
  const float* be2 = (const float*)d_in[12];
  const float* mu2 = (const float*)d_in[13];
  const float* va2 = (const float*)d_in[14];

  const size_t QKV = (size_t)64 * 1600 * 64;  // 6,553,600 bf16 elems
  // split-2 needs: q,k,vt + po[2] (5*QKV) + y,yt + weights, all bf16,
  // plus ls = 2*102400 f32.  ~73.3 MB. Fallback to split-1 (round-10 path).
  size_t elems2 = 5 * QKV + 2 * 1638400 + 147456 + 4096 + 49152;
  size_t need2 = elems2 * 2 + 2 * 102400 * 4 + 256;
  int split = (ws_size >= need2) ? 2 : 1;

  bf16* qw  = (bf16*)d_ws;
  bf16* kw  = qw + QKV;
  bf16* vtw = kw + QKV;
  bf16* pow_ = vtw + QKV;                      // po half0 == ot for conv9
  bf16* yw  = pow_ + (size_t)split * QKV;
  bf16* ytw = yw + 1638400;
  bf16* Wt  = ytw + 1638400;
  bf16* WfT = Wt + 147456;
  bf16* WqT = WfT + 4096;
  float* ls = (float*)(WqT + 49152);           // only touched when split==2

  k_prep<<<576, 256, 0, stream>>>(Wo, Wf, Wq, Wt, WfT, WqT);
  k_qkv<<<1600, 64, 0, stream>>>(x, WqT, bq, qw, kw, vtw);
  k_attn<<<split * 1600, 128, 0, stream>>>(qw, kw, vtw, pow_, ls, split);
  if (split == 2) k_comb<<<3200, 256, 0, stream>>>(pow_, ls, pow_);
  dim3 gc(50, 16);
  k_conv9<<<gc, 128, 0, stream>>>(pow_, Wt, bo, g1, be1, mu1, va1, x, yw, ytw);
  k_ff<<<gc, 128, 0, stream>>>(ytw, WfT, yw, bff, g2, be2, mu2, va2, (float*)d_out);
}

// Round 15
// 252.089 us; speedup vs baseline: 1.3854x; 1.0473x over previous
//
#include <hip/hip_runtime.h>
#include <hip/hip_bf16.h>

// Problem constants (fixed by setup_inputs)
#define NB 16     // batch
#define CC 64     // channels
#define TT 64
#define VV 25
#define LL 1600   // T*V
#define HH 4
#define DD 64
#define NH 64     // N*H

// Dtype contract (rounds 0-3): d_in fp32, d_out fp32, tolerance bf16-grade.
// Round-13 lesson: mfma_16x16x16 costs the same cycles as 16x16x32 -> use
// largest-K shapes only. Round-14 lesson: block supply != concurrency; the
// residency cap (~2.7 blocks/CU) is structural -> attack the non-attn kernels.

typedef __hip_bfloat16 bf16;
typedef __attribute__((ext_vector_type(8))) short short8;
typedef __attribute__((ext_vector_type(4))) float f32x4;
typedef __attribute__((ext_vector_type(4))) unsigned short us4;

__device__ __forceinline__ float b2f(bf16 v) { return __bfloat162float(v); }
__device__ __forceinline__ unsigned short f2bf_bits(float f) {
  bf16 h = __float2bfloat16(f);
  return *(unsigned short*)&h;
}
// pack two f32 -> bf16x2 by truncation: one v_perm_b32 (validated round 14)
__device__ __forceinline__ unsigned pkbf_trunc(float lo, float hi) {
  return __builtin_amdgcn_perm(__float_as_uint(hi), __float_as_uint(lo), 0x07060302u);
}
// xor-1 lane exchange via DPP quad_perm [1,0,3,2] (0xB1): VALU, not LDS.
__device__ __forceinline__ float dppx1(float x) {
  return __int_as_float(
      __builtin_amdgcn_mov_dpp(__float_as_int(x), 0xB1, 0xF, 0xF, true));
}
__device__ __forceinline__ int dppx1i(int x) {
  return __builtin_amdgcn_mov_dpp(x, 0xB1, 0xF, 0xF, true);
}

// ---------------------------------------------------------------------------
// K0: weight prep (unchanged).
// ---------------------------------------------------------------------------
__global__ void k_prep(const float* __restrict__ Wo, const float* __restrict__ Wf,
                       const float* __restrict__ Wq,
                       bf16* __restrict__ Wt, bf16* __restrict__ WfT,
                       bf16* __restrict__ WqT) {
  int i = blockIdx.x * 256 + threadIdx.x;
  if (i < 147456) {
    int j = i & 7, lane = (i >> 3) & 63, cot = (i >> 9) & 3;
    int kc = (i >> 11) & 7, r = i >> 14;
    int co = cot * 16 + (lane & 15);
    int ci = kc * 32 + (lane >> 4) * 8 + j;
    Wt[i] = __float2bfloat16(Wo[(co * 256 + ci) * 9 + r]);
  }
  if (i < 4096) {
    int j = i & 7, lane = (i >> 3) & 63, cot = (i >> 9) & 3, kc = (i >> 11) & 1;
    int co = cot * 16 + (lane & 15);
    int ci = kc * 32 + (lane >> 4) * 8 + j;
    WfT[i] = __float2bfloat16(Wf[co * 64 + ci]);
  }
  if (i < 49152) {
    int jj = i & 7, lane = (i >> 3) & 63, g = i >> 9;  // g 0..95
    int nt = g % 48, half = g / 48;
    int ch = half * 32 + (lane >> 4) * 8 + jj;
    int j = nt * 16 + (lane & 15);
    WqT[i] = __float2bfloat16(Wq[ch * 768 + j]);
  }
}

// ---------------------------------------------------------------------------
// K1: qkv projection as MFMA GEMM, round-15: flat 12-group loop with B-frag
// PREFETCH across the transpose clobbers (round-9 trick: clobbers pin the
// issue point early; waits land at next group's MFMAs). Groups 0-3 = q,
// 4-7 = k (tile-transpose epilogue), 8-11 = v (direct stores).
// grid 1600, block 64.
// ---------------------------------------------------------------------------
__global__ __launch_bounds__(64)
void k_qkv(const float* __restrict__ x, const bf16* __restrict__ WqT,
           const float* __restrict__ bq,
           bf16* __restrict__ q, bf16* __restrict__ k, bf16* __restrict__ vt) {
  __shared__ short xa[16 * 72];  // A-tile [16 l][64 c] (+pad)
  __shared__ short tr[16 * 66];  // transpose buffer for q/k epilogue
  int lane = threadIdx.x;
  int quad = lane >> 4, c = lane & 15;
  int n = blockIdx.x / 100;
  int l0 = (blockIdx.x % 100) * 16;
  bool ev = (c & 1) == 0;

  {
    int l = c;
    const float* xb = x + (size_t)n * 102400 + (size_t)(quad * 16) * 1600 + l0 + l;
    unsigned short vb[16];
#pragma unroll
    for (int i = 0; i < 16; i++) vb[i] = f2bf_bits(xb[(size_t)i * 1600]);
    unsigned wrds[8];
#pragma unroll
    for (int i = 0; i < 8; i++)
      wrds[i] = ((unsigned)vb[2 * i + 1] << 16) | vb[2 * i];
    *(short8*)(xa + l * 72 + quad * 16) = *(short8*)&wrds[0];
    *(short8*)(xa + l * 72 + quad * 16 + 8) = *(short8*)&wrds[4];
  }
  asm volatile("" ::: "memory");
  short8 af0 = *(const short8*)(xa + c * 72 + quad * 8);
  short8 af1 = *(const short8*)(xa + c * 72 + 32 + quad * 8);

  const short* wq0 = (const short*)WqT;
  const float QSCALE = 0.125f * 1.44269504f;

  short8 bc[8], bn[8];
#pragma unroll
  for (int t = 0; t < 4; t++) {
    bc[2 * t]     = *(const short8*)(wq0 + ((size_t)t * 64 + lane) * 8);
    bc[2 * t + 1] = *(const short8*)(wq0 + ((size_t)(48 + t) * 64 + lane) * 8);
  }

#pragma unroll
  for (int g = 0; g < 12; g++) {
    int s = g >> 2, h = g & 3;
    // --- 4 output tiles of this group (uses prefetched bc) ---
    f32x4 z[4];
#pragma unroll
    for (int t = 0; t < 4; t++) {
      int nt = g * 4 + t;
      float bv = bq[nt * 16 + c];
      f32x4 zz = {bv, bv, bv, bv};
      zz = __builtin_amdgcn_mfma_f32_16x16x32_bf16(af0, bc[2 * t], zz, 0, 0, 0);
      zz = __builtin_amdgcn_mfma_f32_16x16x32_bf16(af1, bc[2 * t + 1], zz, 0, 0, 0);
      z[t] = zz;
    }
    // --- prefetch group g+1 B-frags BEFORE the clobber section ---
    if (g < 11) {
#pragma unroll
      for (int t = 0; t < 4; t++) {
        int nt = (g + 1) * 4 + t;
        bn[2 * t]     = *(const short8*)(wq0 + ((size_t)nt * 64 + lane) * 8);
        bn[2 * t + 1] = *(const short8*)(wq0 + ((size_t)(48 + nt) * 64 + lane) * 8);
      }
    }
    if (s < 2) {
      // q/k: tile-transpose via tr, coalesced 16B row stores
      asm volatile("" ::: "memory");
#pragma unroll
      for (int t = 0; t < 4; t++) {
        if (s == 0) {
#pragma unroll
          for (int r = 0; r < 4; r++) z[t][r] *= QSCALE;
        }
        int us_[4];
#pragma unroll
        for (int r = 0; r < 4; r++) us_[r] = f2bf_bits(z[t][r]);
        int xv0 = dppx1i(us_[0]);
        int xv1 = dppx1i(us_[1]);
        int xv2 = dppx1i(us_[2]);
        int xv3 = dppx1i(us_[3]);
        if (ev) {
          *(int*)(tr + (quad * 4 + 0) * 66 + t * 16 + c) = (xv0 << 16) | us_[0];
          *(int*)(tr + (quad * 4 + 1) * 66 + t * 16 + c) = (xv1 << 16) | us_[1];
        } else {
          *(int*)(tr + (quad * 4 + 2) * 66 + t * 16 + (c - 1)) = (us_[2] << 16) | xv2;
          *(int*)(tr + (quad * 4 + 3) * 66 + t * 16 + (c - 1)) = (us_[3] << 16) | xv3;
        }
      }
      asm volatile("" ::: "memory");
      int row = lane >> 2, seg = lane & 3;
      short8 o0 = *(const short8*)(tr + row * 66 + seg * 16);
      short8 o1 = *(const short8*)(tr + row * 66 + seg * 16 + 8);
      short* dstp = (short*)(s == 0 ? q : k);
      short* dst = dstp + ((size_t)(n * 4 + h) * 1600 + l0 + row) * 64 + seg * 16;
      *(short8*)(dst) = o0;
      *(short8*)(dst + 8) = o1;
      asm volatile("" ::: "memory");  // tr reused next group
    } else {
      // v: direct stores to vt[nh][d][l]
#pragma unroll
      for (int t = 0; t < 4; t++) {
        us4 pk;
#pragma unroll
        for (int r = 0; r < 4; r++) pk[r] = f2bf_bits(z[t][r]);
        *(us4*)((short*)vt + ((size_t)((n * 4 + h) * 64 + t * 16 + c)) * 1600 +
                l0 + quad * 4) = pk;
      }
    }
#pragma unroll
    for (int i = 0; i < 8; i++) bc[i] = bn[i];
  }
}

// ---------------------------------------------------------------------------
// K2: MFMA flash attention (round-14 structure, 117 us: split-KV fixed-max,
// XCD swizzle, K LDS-staged w/ prefetch, v_perm pack). Unchanged.
// ---------------------------------------------------------------------------
__global__ __launch_bounds__(128, 2)
void k_attn(const bf16* __restrict__ q, const bf16* __restrict__ k,
            const bf16* __restrict__ vt, bf16* __restrict__ po,
            float* __restrict__ ls, int split) {
  __shared__ short kbuf[64 * 72];    // K tile, padded rows
  __shared__ short pl_all[2][2304];  // per wave: 2 tiles of [16 m][72 j]
  int tid = threadIdx.x;
  int wv = tid >> 6, lane = tid & 63;
  int quad = lane >> 4, c = lane & 15;
  int bid = blockIdx.x;
  int xcd = bid & 7;
  int slot = bid >> 3;
  int half, qt, grp;
  if (split == 2) { half = slot & 1; qt = (slot >> 1) % 25; grp = slot / 50; }
  else            { half = 0;        qt = slot % 25;        grp = slot / 25; }
  int nh = grp * 8 + xcd;          // nh%8 == bid%8 -> per-XCD K/V stream
  int kt0 = half ? 13 : 0;
  int kt1 = (split == 2 && half == 0) ? 13 : 25;
  int l0 = qt * 64 + wv * 32;      // wave's rows: tiles at l0, l0+16
  short* pl = pl_all[wv];

  const short* qbase = (const short*)q + ((size_t)nh * 1600 + l0 + c) * 64 + quad * 8;
  short8 qf[2][2];
  qf[0][0] = *(const short8*)(qbase);
  qf[0][1] = *(const short8*)(qbase + 32);
  qf[1][0] = *(const short8*)(qbase + 16 * 64);
  qf[1][1] = *(const short8*)(qbase + 16 * 64 + 32);

  short ob = (c == 0) ? (short)0x3F80 : (short)0;  // bf16 1.0 in col 0
  short8 onesf = {ob, ob, ob, ob, ob, ob, ob, ob};

  f32x4 acc[2][5] = {};  // per tile: 4 d-tiles + l-tile (ones-trick)

  const short* kg = (const short*)k + (size_t)nh * 102400;
  const short* vg = (const short*)vt + (size_t)nh * 102400;
  bool ev = (c & 1) == 0;
  int cbase = c & ~1;

  short8 sk[4];
  {
    const short8* gk = (const short8*)(kg + kt0 * 4096);
#pragma unroll
    for (int i = 0; i < 4; i++) sk[i] = gk[tid + i * 128];
  }

  for (int kt = kt0; kt < kt1; kt++) {
    __syncthreads();
#pragma unroll
    for (int i = 0; i < 4; i++) {
      int ch = tid + i * 128;
      *(short8*)(kbuf + (ch >> 3) * 72 + (ch & 7) * 8) = sk[i];
    }
    __syncthreads();
    short8 vf[4][2];
#pragma unroll
    for (int ct = 0; ct < 4; ct++) {
      const short* p0 = vg + (size_t)(ct * 16 + c) * 1600 + kt * 64 + quad * 8;
      vf[ct][0] = *(const short8*)(p0);
      vf[ct][1] = *(const short8*)(p0 + 32);
    }
    if (kt + 1 < kt1) {
      const short8* gk = (const short8*)(kg + (kt + 1) * 4096);
#pragma unroll
      for (int i = 0; i < 4; i++) sk[i] = gk[tid + i * 128];
    }
    f32x4 s[2][4];
#pragma unroll
    for (int ct = 0; ct < 4; ct++) {
      short8 kf0 = *(const short8*)(kbuf + (ct * 16 + c) * 72 + quad * 8);
      short8 kf1 = *(const short8*)(kbuf + (ct * 16 + c) * 72 + 32 + quad * 8);
      f32x4 z0 = {-8.f, -8.f, -8.f, -8.f}, z1 = {-8.f, -8.f, -8.f, -8.f};
      z0 = __builtin_amdgcn_mfma_f32_16x16x32_bf16(qf[0][0], kf0, z0, 0, 0, 0);
      z0 = __builtin_amdgcn_mfma_f32_16x16x32_bf16(qf[0][1], kf1, z0, 0, 0, 0);
      z1 = __builtin_amdgcn_mfma_f32_16x16x32_bf16(qf[1][0], kf0, z1, 0, 0, 0);
      z1 = __builtin_amdgcn_mfma_f32_16x16x32_bf16(qf[1][1], kf1, z1, 0, 0, 0);
      s[0][ct] = z0;
      s[1][ct] = z1;
    }
#pragma unroll
    for (int tt = 0; tt < 2; tt++)
#pragma unroll
      for (int ct = 0; ct < 4; ct++)
#pragma unroll
        for (int r = 0; r < 4; r++) s[tt][ct][r] = exp2f(s[tt][ct][r]);
    asm volatile("" ::: "memory");
#pragma unroll
    for (int tt = 0; tt < 2; tt++) {
      short* plt = pl + tt * 1152;
#pragma unroll
      for (int ct = 0; ct < 4; ct++) {
        float x0 = dppx1(s[tt][ct][0]);
        float x1 = dppx1(s[tt][ct][1]);
        float x2 = dppx1(s[tt][ct][2]);
        float x3 = dppx1(s[tt][ct][3]);
        float lo0 = ev ? s[tt][ct][0] : x2;
        float hi0 = ev ? x0 : s[tt][ct][2];
        float lo1 = ev ? s[tt][ct][1] : x3;
        float hi1 = ev ? x1 : s[tt][ct][3];
        int r0 = ev ? 0 : 2, r1 = ev ? 1 : 3;
        unsigned w0 = pkbf_trunc(lo0, hi0);
        unsigned w1 = pkbf_trunc(lo1, hi1);
        *(unsigned*)(plt + (quad * 4 + r0) * 72 + ct * 16 + cbase) = w0;
        *(unsigned*)(plt + (quad * 4 + r1) * 72 + ct * 16 + cbase) = w1;
      }
    }
    asm volatile("" ::: "memory");
    short8 pf[2][2];
#pragma unroll
    for (int tt = 0; tt < 2; tt++) {
      pf[tt][0] = *(const short8*)(pl + tt * 1152 + c * 72 + quad * 8);
      pf[tt][1] = *(const short8*)(pl + tt * 1152 + c * 72 + 32 + quad * 8);
    }
#pragma unroll
    for (int ct = 0; ct < 4; ct++) {
#pragma unroll
      for (int tt = 0; tt < 2; tt++) {
        acc[tt][ct] = __builtin_amdgcn_mfma_f32_16x16x32_bf16(pf[tt][0], vf[ct][0], acc[tt][ct], 0, 0, 0);
        acc[tt][ct] = __builtin_amdgcn_mfma_f32_16x16x32_bf16(pf[tt][1], vf[ct][1], acc[tt][ct], 0, 0, 0);
      }
    }
#pragma unroll
    for (int tt = 0; tt < 2; tt++) {
      acc[tt][4] = __builtin_amdgcn_mfma_f32_16x16x32_bf16(pf[tt][0], onesf, acc[tt][4], 0, 0, 0);
      acc[tt][4] = __builtin_amdgcn_mfma_f32_16x16x32_bf16(pf[tt][1], onesf, acc[tt][4], 0, 0, 0);
    }
  }
  int n = nh >> 2, h = nh & 3;
#pragma unroll
  for (int tt = 0; tt < 2; tt++) {
    float linv[4] = {1.f, 1.f, 1.f, 1.f};
    if (split == 1) {
#pragma unroll
      for (int r = 0; r < 4; r++)
        linv[r] = 1.0f / __shfl(acc[tt][4][r], lane & 48);
    }
    asm volatile("" ::: "memory");
#pragma unroll
    for (int t = 0; t < 4; t++) {
      int us_[4];
#pragma unroll
      for (int r = 0; r < 4; r++) us_[r] = f2bf_bits(acc[tt][t][r] * linv[r]);
      int xv0 = dppx1i(us_[0]);
      int xv1 = dppx1i(us_[1]);
      int xv2 = dppx1i(us_[2]);
      int xv3 = dppx1i(us_[3]);
      if (ev) {
        *(int*)(pl + (quad * 4 + 0) * 66 + t * 16 + c) = (xv0 << 16) | us_[0];
        *(int*)(pl + (quad * 4 + 1) * 66 + t * 16 + c) = (xv1 << 16) | us_[1];
      } else {
        *(int*)(pl + (quad * 4 + 2) * 66 + t * 16 + (c - 1)) = (us_[2] << 16) | xv2;
        *(int*)(pl + (quad * 4 + 3) * 66 + t * 16 + (c - 1)) = (us_[3] << 16) | xv3;
      }
    }
    asm volatile("" ::: "memory");
    int row = lane >> 2, seg = lane & 3;
    short8 o0 = *(const short8*)(pl + row * 66 + seg * 16);
    short8 o1 = *(const short8*)(pl + row * 66 + seg * 16 + 8);
    short* dst = (short*)po + (size_t)half * 6553600 +
                 ((size_t)n * 1600 + l0 + tt * 16 + row) * 256 + h * 64 + seg * 16;
    *(short8*)(dst) = o0;
    *(short8*)(dst + 8) = o1;
    if (split == 2 && c == 0) {
#pragma unroll
      for (int r = 0; r < 4; r++)
        ls[half * 102400 + nh * 1600 + l0 + tt * 16 + quad * 4 + r] = acc[tt][4][r];
    }
    asm volatile("" ::: "memory");
  }
}

// ---------------------------------------------------------------------------
// K2b: combine split-KV partials (unchanged).
// ---------------------------------------------------------------------------
__global__ void k_comb(const bf16* po_in, const float* __restrict__ ls, bf16* ot) {
  int i = blockIdx.x * 256 + threadIdx.x;
  int ch8 = i & 31;
  int rest = i >> 5;
  int l = rest % 1600;
  int n = rest / 1600;
  int nh = n * 4 + (ch8 >> 3);
  float inv = 1.0f / (ls[nh * 1600 + l] + ls[102400 + nh * 1600 + l]);
  const short* a = (const short*)po_in + (size_t)rest * 256 + ch8 * 8;
  short8 av = *(const short8*)a;
  short8 bv = *(const short8*)(a + 6553600);
  unsigned short o8[8];
#pragma unroll
  for (int j = 0; j < 8; j++) {
    float fa = __uint_as_float(((unsigned)(unsigned short)av[j]) << 16);
    float fb = __uint_as_float(((unsigned)(unsigned short)bv[j]) << 16);
    o8[j] = f2bf_bits((fa + fb) * inv);
  }
  *(short8*)((short*)ot + (size_t)rest * 256 + ch8 * 8) = *(short8*)o8;
}

// ---------------------------------------------------------------------------
// K3: fused (1,9)conv+BN1+res+relu  ->  1x1conv+BN2+res+relu -> d_out.
// Round-15 fusion: the y^T tile built in LDS (formerly for the yt store) IS
// the ff GEMM's A-operand, and outv regs ARE ff's residual -> append 8 MFMAs
// + BN2 epilogue, delete k_ff and all y/yt global traffic.
// grid (50,16), block 128 (2 waves). No __syncthreads.
// ---------------------------------------------------------------------------
__global__ void k_conv9(const bf16* __restrict__ ot, const bf16* __restrict__ Wt,
                        const float* __restrict__ bo, const float* __restrict__ g1,
                        const float* __restrict__ be1, const float* __restrict__ mu1,
                        const float* __restrict__ va1, const float* __restrict__ x,
                        const bf16* __restrict__ WfT, const float* __restrict__ bff,
                        const float* __restrict__ g2, const float* __restrict__ be2,
                        const float* __restrict__ mu2, const float* __restrict__ va2,
                        float* __restrict__ out) {
  __shared__ short tl[2][16 * 66];
  int wv = threadIdx.x >> 6;
  int lane = threadIdx.x & 63;
  int quad = lane >> 4, c = lane & 15;
  int n = blockIdx.y;
  int l0 = blockIdx.x * 32 + wv * 16;
  int la = l0 + c;
  int va = la % 25;
  const short* obase = (const short*)ot + (size_t)n * 409600;
  const short* wbase = (const short*)Wt;
  f32x4 acc[4] = {};
  for (int r = 0; r < 9; r++) {
    int sh = r - 4;
    bool valid = (unsigned)(va + sh) < 25u;
    int lp = la + sh;
    lp = max(0, min(1599, lp));
    const short* arow = obase + (size_t)lp * 256 + quad * 8;
    const short* wrow = wbase + (size_t)r * 8 * 4 * 64 * 8 + lane * 8;
    short8 z8 = {0, 0, 0, 0, 0, 0, 0, 0};
#pragma unroll 4
    for (int kc = 0; kc < 8; kc++) {
      short8 af = *(const short8*)(arow + kc * 32);
      af = valid ? af : z8;
      const short* wk = wrow + kc * 4 * 64 * 8;
      short8 b0 = *(const short8*)(wk);
      short8 b1 = *(const short8*)(wk + 512);
      short8 b2 = *(const short8*)(wk + 1024);
      short8 b3 = *(const short8*)(wk + 1536);
      acc[0] = __builtin_amdgcn_mfma_f32_16x16x32_bf16(af, b0, acc[0], 0, 0, 0);
      acc[1] = __builtin_amdgcn_mfma_f32_16x16x32_bf16(af, b1, acc[1], 0, 0, 0);
      acc[2] = __builtin_amdgcn_mfma_f32_16x16x32_bf16(af, b2, acc[2], 0, 0, 0);
      acc[3] = __builtin_amdgcn_mfma_f32_16x16x32_bf16(af, b3, acc[3], 0, 0, 0);
    }
  }
  // --- epilogue 1: BN1 + bias + residual x + relu -> outv (regs only) ---
  short* tlw = &tl[wv][0];
  float outv[4][4];
#pragma unroll
  for (int cot = 0; cot < 4; cot++) {
    int co = cot * 16 + c;
    float inv = g1[co] * rsqrtf(va1[co] + 1e-5f);
    float add = be1[co] - mu1[co] * inv + bo[co] * inv;
    f32x4 xr = *(const f32x4*)(x + (size_t)(n * 64 + co) * 1600 + l0 + quad * 4);
#pragma unroll
    for (int rr = 0; rr < 4; rr++)
      outv[cot][rr] = fmaxf(acc[cot][rr] * inv + add + xr[rr], 0.f);
  }
  // --- y^T tile via wave-private LDS [16 l][66 ci] (DPP pairing) ---
  asm volatile("" ::: "memory");
  bool ev = (c & 1) == 0;
#pragma unroll
  for (int cot = 0; cot < 4; cot++) {
    int us_[4];
#pragma unroll
    for (int rr = 0; rr < 4; rr++) us_[rr] = f2bf_bits(outv[cot][rr]);
    int xv0 = dppx1i(us_[0]);
    int xv1 = dppx1i(us_[1]);
    int xv2 = dppx1i(us_[2]);
    int xv3 = dppx1i(us_[3]);
    if (ev) {
      *(int*)(tlw + (quad * 4 + 0) * 66 + cot * 16 + c) = (xv0 << 16) | us_[0];
      *(int*)(tlw + (quad * 4 + 1) * 66 + cot * 16 + c) = (xv1 << 16) | us_[1];
    } else {
      *(int*)(tlw + (quad * 4 + 2) * 66 + cot * 16 + (c - 1)) = (us_[2] << 16) | xv2;
      *(int*)(tlw + (quad * 4 + 3) * 66 + cot * 16 + (c - 1)) = (us_[3] << 16) | xv3;
    }
  }
  asm volatile("" ::: "memory");
  // --- fused ff: A-frags straight from tl (A[m=l][k=ci]) ---
  short8 afY0 = *(const short8*)(tlw + c * 66 + quad * 8);
  short8 afY1 = *(const short8*)(tlw + c * 66 + 32 + quad * 8);
  const short* wfb = (const short*)WfT + lane * 8;
  f32x4 acc2[4] = {};
#pragma unroll
  for (int kc = 0; kc < 2; kc++) {
    short8 afk = kc ? afY1 : afY0;
    const short* wk = wfb + kc * 2048;
    short8 b0 = *(const short8*)(wk);
    short8 b1 = *(const short8*)(wk + 512);
    short8 b2 = *(const short8*)(wk + 1024);
    short8 b3 = *(const short8*)(wk + 1536);
    acc2[0] = __builtin_amdgcn_mfma_f32_16x16x32_bf16(afk, b0, acc2[0], 0, 0, 0);
    acc2[1] = __builtin_amdgcn_mfma_f32_16x16x32_bf16(afk, b1, acc2[1], 0, 0, 0);
    acc2[2] = __builtin_amdgcn_mfma_f32_16x16x32_bf16(afk, b2, acc2[2], 0, 0, 0);
    acc2[3] = __builtin_amdgcn_mfma_f32_16x16x32_bf16(afk, b3, acc2[3], 0, 0, 0);
  }
  // --- epilogue 2: BN2 + bias + residual y(=outv) + relu -> d_out fp32 ---
#pragma unroll
  for (int cot = 0; cot < 4; cot++) {
    int co = cot * 16 + c;
    float inv = g2[co] * rsqrtf(va2[co] + 1e-5f);
    float add = be2[co] - mu2[co] * inv + bff[co] * inv;
    f32x4 ov;
#pragma unroll
    for (int rr = 0; rr < 4; rr++)
      ov[rr] = fmaxf(acc2[cot][rr] * inv + add + outv[cot][rr], 0.f);
    *(f32x4*)(out + (size_t)(n * 64 + co) * 1600 + l0 + quad * 4) = ov;
  }
}

extern "C" void kernel_launch(void* const* d_in, const int* in_sizes, int n_in,
                              void* d_out, int out_size, void* d_ws, size_t ws_size,
                              hipStream_t stream) {
  const float* x   = (const float*)d_in[0];
  const float* Wq  = (const float*)d_in[1];
  const float* bq  = (const float*)d_in[2];
  const float* Wo  = (const float*)d_in[3];
  const float* bo  = (const float*)d_in[4];
  const float* g1  = (const float*)d_in[5];
  const float* be1 = (const float*)d_in[6];
  const float* mu1 = (const float*)d_in[7];
  const float* va1 = (const float*)d_in[8];
  const float* Wf  = (const float*)d_in[9];
  const float* bff = (const float*)d_in[10];
  const float* g2  = (const float*)d_in[11];
  const float* be2 = (const float*)d_in[12];
  const float* mu2 = (const float*)d_in[13];
  const float* va2 = (const float*)d_in[14];

  const size_t QKV = (size_t)64 * 1600 * 64;  // 6,553,600 bf16 elems
  // split-2: q,k,vt + po[2] (5*QKV) + weights; ls = 2*102400 f32. ~66.7 MB.
  size_t elems2 = 5 * QKV + 147456 + 4096 + 49152;
  size_t need2 = elems2 * 2 + 2 * 102400 * 4 + 256;
  int split = (ws_size >= need2) ? 2 : 1;

  bf16* qw  = (bf16*)d_ws;
  bf16* kw  = qw + QKV;
  bf16* vtw = kw + QKV;
  bf16* pow_ = vtw + QKV;                      // po half0 == ot for conv9
  bf16* Wt  = pow_ + (size_t)split * QKV;
  bf16* WfT = Wt + 147456;
  bf16* WqT = WfT + 4096;
  float* ls = (float*)(WqT + 49152);           // only touched when split==2

  k_prep<<<576, 256, 0, stream>>>(Wo, Wf, Wq, Wt, WfT, WqT);
  k_qkv<<<1600, 64, 0, stream>>>(x, WqT, bq, qw, kw, vtw);
  k_attn<<<split * 1600, 128, 0, stream>>>(qw, kw, vtw, pow_, ls, split);
  if (split == 2) k_comb<<<3200, 256, 0, stream>>>(pow_, ls, pow_);
  dim3 gc(50, 16);
  k_conv9<<<gc, 128, 0, stream>>>(pow_, Wt, bo, g1, be1, mu1, va1, x,
                                  WfT, bff, g2, be2, mu2, va2, (float*)d_out);
}